// Round 2
// baseline (1017.055 us; speedup 1.0000x reference)
//
#include <hip/hip_runtime.h>
#include <math.h>

#define EPB 256   // edges per block

typedef float f32x2 __attribute__((ext_vector_type(2)));
typedef float f32x4 __attribute__((ext_vector_type(4)));

// ---------------------------------------------------------------------------
// Prologue: fold Wf into W2/b2, detect edge_index dtype (int32 vs int64).
//   ws[0..2047]   : W2ft[j][d] = (Wf @ W2)[d][j]   (transposed, 32x64)
//   ws[2048..2111]: b2f[d] = Wf @ b2 + bf
//   ((int*)ws)[2112]: 1 if edge_index is int64, 0 if int32
// ---------------------------------------------------------------------------
__global__ void lfpe_precompute(const float* __restrict__ W2,   // (64,32)
                                const float* __restrict__ b2,   // (64)
                                const float* __restrict__ Wf,   // (64,64)
                                const float* __restrict__ bf,   // (64)
                                const int* __restrict__ eidx32,
                                float* __restrict__ ws) {
    const int t = threadIdx.x;  // 256 threads
    for (int idx = t; idx < 2048; idx += 256) {
        const int j = idx >> 6, d = idx & 63;
        float s = 0.f;
        #pragma unroll 8
        for (int k = 0; k < 64; ++k) s += Wf[d * 64 + k] * W2[k * 32 + j];
        ws[j * 64 + d] = s;
    }
    if (t < 64) {
        float s = bf[t];
        #pragma unroll 8
        for (int k = 0; k < 64; ++k) s += Wf[t * 64 + k] * b2[k];
        ws[2048 + t] = s;
    }
    // dtype sniff: for int64 data (indices < 2^31) every odd 32-bit word of
    // the first 64 entries is 0; for int32 data they are random in [0,50000).
    __shared__ int nz;
    if (t == 0) nz = 0;
    __syncthreads();
    if (t < 64 && eidx32[2 * t + 1] != 0) atomicAdd(&nz, 1);
    __syncthreads();
    if (t == 0) ((int*)ws)[2112] = (nz == 0) ? 1 : 0;
}

// ---------------------------------------------------------------------------
// Main kernel: two phases per block of 256 edges.
//  Phase 1: one thread per edge -> geom -> Fourier -> GELU MLP hidden h[32],
//           stored to LDS in float4-chunked [j4][edge][4] layout
//           (contiguous wave writes; phase-2 reads are broadcasts).
//  Phase 2: lane owns channel pair d2=(tid&31)*2; half-wave per edge;
//           dwordx2 fully-coalesced nontemporal IO.
// ---------------------------------------------------------------------------
__global__ __launch_bounds__(256) void lfpe_main(
    const float* __restrict__ edge_attr,
    const float* __restrict__ coords,
    const void*  __restrict__ eidx,
    const float* __restrict__ Wr,      // (32,7)
    const float* __restrict__ W1,      // (32,64)
    const float* __restrict__ b1,      // (32)
    const float* __restrict__ ws,      // W2ft | b2f | flag
    float* __restrict__ out,
    const int E)
{
    __shared__ float sWr[32 * 8];      // Wr rows padded to 8
    __shared__ float sW1p[32 * 64];    // idx=i*64+r: W1[r>>1][(r&1)*32 + i]
    __shared__ float sb1[32];
    __shared__ f32x4 sh4[8 * EPB];     // h chunks: [j4][el]

    const int tid = threadIdx.x;

    // ---- stage weights (tiny; L2-hot after first blocks) ----
    for (int idx = tid; idx < 2048; idx += 256) {
        const int i = idx >> 6, r = idx & 63;
        sW1p[idx] = W1[(r >> 1) * 64 + (r & 1) * 32 + i];
    }
    {
        const int i = tid >> 3, m = tid & 7;
        sWr[tid] = (m < 7) ? Wr[i * 7 + m] : 0.f;
    }
    if (tid < 32) sb1[tid] = b1[tid];

    const int is64 = ((const int*)ws)[2112];
    const int e = blockIdx.x * EPB + tid;

    float acc[32];
    #pragma unroll
    for (int j = 0; j < 32; ++j) acc[j] = 0.f;

    __syncthreads();

    // ---------------- phase 1: per-edge hidden vector ----------------
    if (e < E) {
        long long u, v;
        if (is64) {
            u = ((const long long*)eidx)[e];
            v = ((const long long*)eidx)[E + e];
        } else {
            u = ((const int*)eidx)[e];
            v = ((const int*)eidx)[E + e];
        }
        const float* cu = coords + 3 * (int)u;
        const float* cv = coords + 3 * (int)v;
        const float ux = cu[0], uy = cu[1], uz = cu[2];
        const float vx = cv[0], vy = cv[1], vz = cv[2];
        float g[7];
        g[0] = vx - ux; g[1] = vy - uy; g[2] = vz - uz;
        g[3] = 0.5f * (ux + vx); g[4] = 0.5f * (uy + vy); g[5] = 0.5f * (uz + vz);
        g[6] = sqrtf(g[0] * g[0] + g[1] * g[1] + g[2] * g[2]);

        #pragma unroll 4
        for (int i = 0; i < 32; ++i) {
            float p = 0.f;
            #pragma unroll
            for (int m = 0; m < 7; ++m) p += g[m] * sWr[i * 8 + m];
            const float c = __cosf(p);
            const float s = __sinf(p);
            const f32x4* wrow = (const f32x4*)&sW1p[i * 64];
            #pragma unroll
            for (int j4 = 0; j4 < 16; ++j4) {
                const f32x4 w = wrow[j4];   // broadcast (uniform addr in wave)
                acc[j4 * 2 + 0] += c * w.x + s * w.y;
                acc[j4 * 2 + 1] += c * w.z + s * w.w;
            }
        }
        #pragma unroll
        for (int j = 0; j < 32; ++j) {
            const float hp = acc[j] * 0.125f + sb1[j];   // 1/sqrt(64) = 0.125
            acc[j] = 0.5f * hp * (1.f + erff(hp * 0.70710678118654752f));
        }
    }

    #pragma unroll
    for (int j4 = 0; j4 < 8; ++j4) {
        f32x4 hv;
        hv.x = acc[4 * j4]; hv.y = acc[4 * j4 + 1];
        hv.z = acc[4 * j4 + 2]; hv.w = acc[4 * j4 + 3];
        sh4[j4 * EPB + tid] = hv;
    }

    __syncthreads();

    // ---------------- phase 2: h @ W2f^T + fuse, coalesced dwordx2 IO -------
    const int d2  = (tid & 31) * 2;  // channel pair
    const int sub = tid >> 5;        // 0..7: edge offset within group of 8
    float w2a[32], w2b[32];
    #pragma unroll
    for (int j = 0; j < 32; ++j) {
        const f32x2 wp = *(const f32x2*)&ws[j * 64 + d2];
        w2a[j] = wp.x; w2b[j] = wp.y;
    }
    const f32x2 bb = *(const f32x2*)&ws[2048 + d2];

    const long long base = (long long)blockIdx.x * EPB;
    const float* ea = edge_attr + base * 64 + sub * 64 + d2;
    float*       op = out       + base * 64 + sub * 64 + d2;

    #pragma unroll 4
    for (int it = 0; it < 32; ++it) {
        const int el = it * 8 + sub;        // half-wave-uniform local edge
        if (base + el < E) {
            const f32x2 av = __builtin_nontemporal_load((const f32x2*)(ea + it * 512));
            float a = bb.x, b = bb.y;
            #pragma unroll
            for (int j4 = 0; j4 < 8; ++j4) {
                const f32x4 hv = sh4[j4 * EPB + el];   // broadcast read
                a += hv.x * w2a[4 * j4]     + hv.y * w2a[4 * j4 + 1] +
                     hv.z * w2a[4 * j4 + 2] + hv.w * w2a[4 * j4 + 3];
                b += hv.x * w2b[4 * j4]     + hv.y * w2b[4 * j4 + 1] +
                     hv.z * w2b[4 * j4 + 2] + hv.w * w2b[4 * j4 + 3];
            }
            f32x2 r; r.x = av.x + a; r.y = av.y + b;
            __builtin_nontemporal_store(r, (f32x2*)(op + it * 512));
        }
    }
}

extern "C" void kernel_launch(void* const* d_in, const int* in_sizes, int n_in,
                              void* d_out, int out_size, void* d_ws, size_t ws_size,
                              hipStream_t stream) {
    const float* edge_attr = (const float*)d_in[0];
    const float* coords    = (const float*)d_in[1];
    const void*  eidx      = (const void*) d_in[2];
    const float* Wr        = (const float*)d_in[3];
    const float* W1        = (const float*)d_in[4];
    const float* b1        = (const float*)d_in[5];
    const float* W2        = (const float*)d_in[6];
    const float* b2        = (const float*)d_in[7];
    const float* Wf        = (const float*)d_in[8];
    const float* bf        = (const float*)d_in[9];
    float* out = (float*)d_out;
    float* ws  = (float*)d_ws;

    const int E = in_sizes[2] / 2;   // edge_index is (2, E)

    hipLaunchKernelGGL(lfpe_precompute, dim3(1), dim3(256), 0, stream,
                       W2, b2, Wf, bf, (const int*)eidx, ws);

    const int nblk = (E + EPB - 1) / EPB;
    hipLaunchKernelGGL(lfpe_main, dim3(nblk), dim3(256), 0, stream,
                       edge_attr, coords, eidx, Wr, W1, b1, ws, out, E);
}

// Round 5
// 891.157 us; speedup vs baseline: 1.1413x; 1.1413x over previous
//
#include <hip/hip_runtime.h>
#include <math.h>

#define EPB 256   // edges per block

typedef float f32x2 __attribute__((ext_vector_type(2)));
typedef float f32x4 __attribute__((ext_vector_type(4)));
typedef _Float16 f16x2 __attribute__((ext_vector_type(2)));

__device__ inline f16x2 as_h2(float f) { union { float f; f16x2 h; } u; u.f = f; return u.h; }
__device__ inline float as_f32(f16x2 h) { union { float f; f16x2 h; } u; u.h = h; return u.f; }

__device__ inline float fdot2f(f16x2 a, f16x2 b, float c) {
#if __has_builtin(__builtin_amdgcn_fdot2)
    return __builtin_amdgcn_fdot2(a, b, c, false);
#else
    return c + (float)a.x * (float)b.x + (float)a.y * (float)b.y;
#endif
}

// ---------------------------------------------------------------------------
// Prologue: fold Wf into W2/b2 (pe@Wf^T+bf == h@(Wf W2)^T + (Wf b2 + bf)),
// pack W2f as f16x2 pairs along j, detect edge_index dtype.
// ws float-slot map:
//   [0..1023]   : W2f half2: slot jp*64+d = (W2f[d][2jp], W2f[d][2jp+1])
//   [1024..1087]: b2f[d] (fp32)
//   [1100]      : (int) 1 if edge_index is int64 else 0
// ---------------------------------------------------------------------------
__global__ void lfpe_precompute(const float* __restrict__ W2,   // (64,32)
                                const float* __restrict__ b2,   // (64)
                                const float* __restrict__ Wf,   // (64,64)
                                const float* __restrict__ bf,   // (64)
                                const int* __restrict__ eidx32,
                                float* __restrict__ ws) {
    const int t = threadIdx.x;  // 256 threads
    for (int idx = t; idx < 1024; idx += 256) {
        const int jp = idx >> 6, d = idx & 63;
        float s0 = 0.f, s1 = 0.f;
        #pragma unroll 8
        for (int k = 0; k < 64; ++k) {
            const float w = Wf[d * 64 + k];
            s0 += w * W2[k * 32 + 2 * jp];
            s1 += w * W2[k * 32 + 2 * jp + 1];
        }
        f16x2 p; p.x = (_Float16)s0; p.y = (_Float16)s1;
        ws[idx] = as_f32(p);
    }
    if (t < 64) {
        float s = bf[t];
        #pragma unroll 8
        for (int k = 0; k < 64; ++k) s += Wf[t * 64 + k] * b2[k];
        ws[1024 + t] = s;
    }
    // dtype sniff: for int64 data (indices < 2^31) every odd 32-bit word of
    // the first 64 entries is 0; for int32 data they are random in [0,50000).
    __shared__ int nz;
    if (t == 0) nz = 0;
    __syncthreads();
    if (t < 64 && eidx32[2 * t + 1] != 0) atomicAdd(&nz, 1);
    __syncthreads();
    if (t == 0) ((int*)ws)[1100] = (nz == 0) ? 1 : 0;
}

// ---------------------------------------------------------------------------
// Main kernel, two phases per 256-edge block, fp16 dot2 datapath.
//  Phase 1: thread=edge: geom(fp32) -> cos/sin(fp32) -> pack f16x2 ->
//           h_pre[j] = sum_i dot2((c,s)_i, (W1[j][i],W1[j][i+32])) ;
//           GELU fp32; h packed to f16x2 pairs in chunked LDS [c][el] f32x4.
//  Phase 2: lane owns channel pair d2=(tid&31)*2, sub=tid>>5 edge subgroup;
//           pe pair via 32 dot2 vs W2f-half2 kept in 32 VGPRs;
//           dwordx2 nontemporal fully-coalesced IO.
// ---------------------------------------------------------------------------
__global__ __launch_bounds__(256) void lfpe_main(
    const float* __restrict__ edge_attr,
    const float* __restrict__ coords,
    const void*  __restrict__ eidx,
    const float* __restrict__ Wr,      // (32,7)
    const float* __restrict__ W1,      // (32,64)
    const float* __restrict__ b1,      // (32)
    const float* __restrict__ ws,      // W2f-h2 | b2f | flag
    float* __restrict__ out,
    const int E)
{
    __shared__ float sWr[32 * 8];      // Wr rows padded to 8       (1 KB)
    __shared__ float sW1h[32 * 32];    // [i*32+j]=h2(W1[j][i],W1[j][i+32]) (4 KB)
    __shared__ float sb1[32];
    __shared__ f32x4 sh2[4 * EPB];     // h f16x2 chunks: [c][el]   (16 KB)

    const int tid = threadIdx.x;

    // ---- stage weights (tiny; L2-hot after first blocks) ----
    for (int idx = tid; idx < 1024; idx += 256) {
        const int i = idx >> 5, j = idx & 31;
        f16x2 p;
        p.x = (_Float16)W1[j * 64 + i];
        p.y = (_Float16)W1[j * 64 + 32 + i];
        sW1h[idx] = as_f32(p);
    }
    {
        const int i = tid >> 3, m = tid & 7;
        sWr[tid] = (m < 7) ? Wr[i * 7 + m] : 0.f;
    }
    if (tid < 32) sb1[tid] = b1[tid];

    const int is64 = ((const int*)ws)[1100];
    const int e = blockIdx.x * EPB + tid;

    float acc[32];
    #pragma unroll
    for (int j = 0; j < 32; ++j) acc[j] = 0.f;

    __syncthreads();

    // ---------------- phase 1: per-edge hidden vector ----------------
    if (e < E) {
        long long u, v;
        if (is64) {
            u = ((const long long*)eidx)[e];
            v = ((const long long*)eidx)[E + e];
        } else {
            u = ((const int*)eidx)[e];
            v = ((const int*)eidx)[E + e];
        }
        const float* cu = coords + 3 * (int)u;
        const float* cv = coords + 3 * (int)v;
        const float ux = cu[0], uy = cu[1], uz = cu[2];
        const float vx = cv[0], vy = cv[1], vz = cv[2];
        float g[7];
        g[0] = vx - ux; g[1] = vy - uy; g[2] = vz - uz;
        g[3] = 0.5f * (ux + vx); g[4] = 0.5f * (uy + vy); g[5] = 0.5f * (uz + vz);
        g[6] = sqrtf(g[0] * g[0] + g[1] * g[1] + g[2] * g[2]);

        #pragma unroll 4
        for (int i = 0; i < 32; ++i) {
            float p = 0.f;
            #pragma unroll
            for (int m = 0; m < 7; ++m) p += g[m] * sWr[i * 8 + m];
            f16x2 cs;
            cs.x = (_Float16)__cosf(p);
            cs.y = (_Float16)__sinf(p);
            const f32x4* wrow = (const f32x4*)&sW1h[i * 32];  // broadcast reads
            #pragma unroll
            for (int r = 0; r < 8; ++r) {
                const f32x4 w = wrow[r];
                acc[r * 4 + 0] = fdot2f(cs, as_h2(w.x), acc[r * 4 + 0]);
                acc[r * 4 + 1] = fdot2f(cs, as_h2(w.y), acc[r * 4 + 1]);
                acc[r * 4 + 2] = fdot2f(cs, as_h2(w.z), acc[r * 4 + 2]);
                acc[r * 4 + 3] = fdot2f(cs, as_h2(w.w), acc[r * 4 + 3]);
            }
        }
        #pragma unroll
        for (int j = 0; j < 32; ++j) {
            const float hp = acc[j] * 0.125f + sb1[j];   // 1/sqrt(64) = 0.125
            acc[j] = 0.5f * hp * (1.f + erff(hp * 0.70710678118654752f));
        }
    }

    #pragma unroll
    for (int c = 0; c < 4; ++c) {
        f32x4 ch;
        #pragma unroll
        for (int q = 0; q < 4; ++q) {
            const int jp = c * 4 + q;
            f16x2 hh;
            hh.x = (_Float16)acc[2 * jp];
            hh.y = (_Float16)acc[2 * jp + 1];
            ch[q] = as_f32(hh);
        }
        sh2[c * EPB + tid] = ch;
    }

    // phase-2 weights: independent of LDS, issue before the barrier
    const int d2  = (tid & 31) * 2;  // channel pair
    const int sub = tid >> 5;        // 0..7: edge offset within group of 8
    f16x2 wA[16], wB[16];
    #pragma unroll
    for (int jp = 0; jp < 16; ++jp) {
        wA[jp] = as_h2(ws[jp * 64 + d2]);
        wB[jp] = as_h2(ws[jp * 64 + d2 + 1]);
    }
    const f32x2 bb = *(const f32x2*)&ws[1024 + d2];

    __syncthreads();

    // ---------------- phase 2: pe = h @ W2f^T + fuse, dwordx2 IO ----------
    const long long base = (long long)blockIdx.x * EPB;
    const float* ea = edge_attr + base * 64 + sub * 64 + d2;
    float*       op = out       + base * 64 + sub * 64 + d2;

    #pragma unroll 4
    for (int it = 0; it < 32; ++it) {
        const int el = it * 8 + sub;        // half-wave-uniform local edge
        if (base + el < E) {
            const f32x2 av = __builtin_nontemporal_load((const f32x2*)(ea + it * 512));
            float a = bb.x, b = bb.y;
            #pragma unroll
            for (int c = 0; c < 4; ++c) {
                const f32x4 hv = sh2[c * EPB + el];   // broadcast read
                #pragma unroll
                for (int q = 0; q < 4; ++q) {
                    const int jp = c * 4 + q;
                    const f16x2 hq = as_h2(hv[q]);
                    a = fdot2f(hq, wA[jp], a);
                    b = fdot2f(hq, wB[jp], b);
                }
            }
            f32x2 r; r.x = av.x + a; r.y = av.y + b;
            __builtin_nontemporal_store(r, (f32x2*)(op + it * 512));
        }
    }
}

extern "C" void kernel_launch(void* const* d_in, const int* in_sizes, int n_in,
                              void* d_out, int out_size, void* d_ws, size_t ws_size,
                              hipStream_t stream) {
    const float* edge_attr = (const float*)d_in[0];
    const float* coords    = (const float*)d_in[1];
    const void*  eidx      = (const void*) d_in[2];
    const float* Wr        = (const float*)d_in[3];
    const float* W1        = (const float*)d_in[4];
    const float* b1        = (const float*)d_in[5];
    const float* W2        = (const float*)d_in[6];
    const float* b2        = (const float*)d_in[7];
    const float* Wf        = (const float*)d_in[8];
    const float* bf        = (const float*)d_in[9];
    float* out = (float*)d_out;
    float* ws  = (float*)d_ws;

    const int E = in_sizes[2] / 2;   // edge_index is (2, E)

    hipLaunchKernelGGL(lfpe_precompute, dim3(1), dim3(256), 0, stream,
                       W2, b2, Wf, bf, (const int*)eidx, ws);

    const int nblk = (E + EPB - 1) / EPB;
    hipLaunchKernelGGL(lfpe_main, dim3(nblk), dim3(256), 0, stream,
                       edge_attr, coords, eidx, Wr, W1, b1, ws, out, E);
}